// Round 9
// baseline (65.627 us; speedup 1.0000x reference)
//
#include <hip/hip_runtime.h>
#include <math.h>

#define NP 16384
#define NG 2048
#define NC 17

#define TSH 3            // tile = 8x8 voxels in (x,y)
#define NTX 25
#define NTY 25
#define NTILE (NTX * NTY)   // 625
#define SEGC 32          // per-wave-range candidate cap (4 ranges of 512 prims)
#define PCAP 128         // per-tile point cap (Poisson mean ~26)

#define GRIDSZ 0.4f
#define PCMINX -40.0f
#define PCMINY -40.0f
#define PCMINZ -1.0f
#define SCALE_MULTC 3.0f

// Kernel A. Blocks 0..624: prim->tile binning (ballot-compacted, per-wave
// 512-prim segment => ascending-g candidate order, deterministic, no atomics).
// Blocks 625..688: point->tile binning via atomicAdd (list ORDER nondet, but
// each point's own output depends only on candidate order => deterministic).
__global__ __launch_bounds__(256)
void bin_kernel(const float* __restrict__ pts,
                const float* __restrict__ means3D,
                const float* __restrict__ scales,
                unsigned int* __restrict__ candCnt,     // packed 4x u8 per tile
                unsigned short* __restrict__ candList,  // [NTILE][4][SEGC]
                unsigned int* __restrict__ ptCnt,       // [NTILE] (pre-zeroed)
                unsigned short* __restrict__ ptList) {  // [NTILE][PCAP]
    int b = blockIdx.x;
    int tid = threadIdx.x;
    if (b < NTILE) {
        __shared__ int wc[4];
        int lane = tid & 63, w = tid >> 6;
        int tx = b % NTX, ty = b / NTX;
        unsigned short* seg = candList + ((size_t)b * 4 + w) * SEGC;
        unsigned cl = 0;
#pragma unroll 2
        for (int it = 0; it < 8; ++it) {
            int g = w * 512 + it * 64 + lane;
            float mx = means3D[g * 3 + 0], my = means3D[g * 3 + 1];
            float sx = scales[g * 3 + 0], sy = scales[g * 3 + 1], sz = scales[g * 3 + 2];
            int vx = (int)floorf((mx - PCMINX) / GRIDSZ);
            int vy = (int)floorf((my - PCMINY) / GRIDSZ);
            float smax = fmaxf(sx, fmaxf(sy, sz));
            int rad = (int)ceilf(smax * SCALE_MULTC / GRIDSZ);
            if (rad < 1) rad = 1;
            // arithmetic >> floors negatives
            bool ov = (((vx - rad) >> TSH) <= tx) & (((vx + rad) >> TSH) >= tx) &
                      (((vy - rad) >> TSH) <= ty) & (((vy + rad) >> TSH) >= ty);
            unsigned long long bal = __ballot(ov);
            if (ov) {
                int pos = (int)cl + (int)__popcll(bal & ((1ull << lane) - 1ull));
                if (pos < SEGC) seg[pos] = (unsigned short)g;
            }
            cl += (unsigned)__popcll(bal);
        }
        if (lane == 0) wc[w] = min((int)cl, SEGC);
        __syncthreads();
        if (tid == 0)
            candCnt[b] = (unsigned)(wc[0] | (wc[1] << 8) | (wc[2] << 16) | (wc[3] << 24));
    } else {
        int p = (b - NTILE) * 256 + tid;
        float x = pts[p * 3 + 0], y = pts[p * 3 + 1];
        int jx = ((int)floorf((x - PCMINX) / GRIDSZ)) >> TSH;
        int jy = ((int)floorf((y - PCMINY) / GRIDSZ)) >> TSH;
        int t = jy * NTX + jx;
        unsigned pos = atomicAdd(&ptCnt[t], 1u);
        if (pos < PCAP) ptList[(size_t)t * PCAP + pos] = (unsigned short)p;
    }
}

// Kernel B: one wave per tile, lane = point. All candidate addresses are
// functions of (blockIdx, k) only => uniform => scalar s_load broadcasts, no
// divergent gathers. Heavy eval only when __any lane hits; predicated per lane.
__global__ __launch_bounds__(64)
void process_kernel(const float* __restrict__ pts,
                    const float* __restrict__ means3D,
                    const float* __restrict__ opas,
                    const float* __restrict__ uu,
                    const float* __restrict__ vv,
                    const float* __restrict__ semantics,
                    const float* __restrict__ scales,
                    const float* __restrict__ rot3D,
                    const unsigned int* __restrict__ candCnt,
                    const unsigned short* __restrict__ candList,
                    const unsigned int* __restrict__ ptCnt,
                    const unsigned short* __restrict__ ptList,
                    float* __restrict__ out) {
    int t = blockIdx.x;
    int lane = threadIdx.x;
    unsigned cpack = candCnt[t];
    int npnt = min((int)ptCnt[t], PCAP);

    for (int base = 0; base < npnt; base += 64) {
        bool act = (base + lane) < npnt;
        int p = act ? (int)ptList[(size_t)t * PCAP + base + lane] : 0;
        float px = pts[p * 3 + 0], py = pts[p * 3 + 1], pz = pts[p * 3 + 2];
        int ix = (int)floorf((px - PCMINX) / GRIDSZ);
        int iy = (int)floorf((py - PCMINY) / GRIDSZ);
        int iz = (int)floorf((pz - PCMINZ) / GRIDSZ);

        float density = 0.0f, logbin = 0.0f;
        float acc[NC];
#pragma unroll
        for (int c = 0; c < NC; ++c) acc[c] = 0.0f;

        for (int s = 0; s < 4; ++s) {
            int cs = (int)((cpack >> (8 * s)) & 0xffu);
            const unsigned short* seg = candList + ((size_t)t * 4 + s) * SEGC;
            for (int k = 0; k < cs; ++k) {
                int g = (int)seg[k];   // uniform -> SGPR
                float mx = means3D[g * 3 + 0], my = means3D[g * 3 + 1], mz = means3D[g * 3 + 2];
                float sx = scales[g * 3 + 0], sy = scales[g * 3 + 1], sz = scales[g * 3 + 2];
                int vx = (int)floorf((mx - PCMINX) / GRIDSZ);
                int vy = (int)floorf((my - PCMINY) / GRIDSZ);
                int vz = (int)floorf((mz - PCMINZ) / GRIDSZ);
                float smax = fmaxf(sx, fmaxf(sy, sz));
                int rad = (int)ceilf(smax * SCALE_MULTC / GRIDSZ);
                if (rad < 1) rad = 1;
                int cheb = max(max(abs(ix - vx), abs(iy - vy)), abs(iz - vz));
                bool hit = cheb <= rad;
                if (__any(hit)) {
                    const float* r = rot3D + (size_t)g * 9;
                    float dx = px - mx, dy = py - my, dz = pz - mz;
                    float l0 = dx * r[0] + dy * r[3] + dz * r[6];
                    float l1 = dx * r[1] + dy * r[4] + dz * r[7];
                    float l2 = dx * r[2] + dy * r[5] + dz * r[8];
                    float t0 = l0 / sx, t1 = l1 / sy, t2 = l2 / sz;
                    float s0 = t0 * t0 + 1e-8f;
                    float s1 = t1 * t1 + 1e-8f;
                    float s2 = t2 * t2 + 1e-8f;
                    float ie1 = 1.0f / uu[g];
                    float ie2 = 1.0f / vv[g];
                    float e21 = vv[g] * ie1;
                    float f = __powf(__powf(s0, ie2) + __powf(s1, ie2), e21) +
                              __powf(s2, ie1);
                    float a = opas[g] * __expf(-0.5f * f);
                    a = hit ? a : 0.0f;
                    density += a;
                    const float* sg = semantics + (size_t)g * NC;
#pragma unroll
                    for (int c = 0; c < NC; ++c) acc[c] = fmaf(a, sg[c], acc[c]);
                    logbin += __logf(1.0f - fminf(a, 1.0f - 1e-4f));
                }
            }
        }

        if (act) {
            float inv = 1.0f / (density + 1e-9f);
#pragma unroll
            for (int c = 0; c < NC; ++c) out[(size_t)p * NC + c] = acc[c] * inv;
            out[(size_t)NP * NC + p] = 1.0f - expf(logbin);
            out[(size_t)NP * NC + NP + p] = density;
        }
    }
}

// ---- fallback (ws too small): monolithic kernel ----
__global__ __launch_bounds__(64)
void agg_kernel_fb(const float* __restrict__ pts,
                   const float* __restrict__ means3D,
                   const float* __restrict__ opas,
                   const float* __restrict__ uu,
                   const float* __restrict__ vv,
                   const float* __restrict__ semantics,
                   const float* __restrict__ scales,
                   const float* __restrict__ rot3D,
                   float* __restrict__ out) {
    int p = blockIdx.x * 64 + threadIdx.x;
    if (p >= NP) return;
    float px = pts[p * 3 + 0], py = pts[p * 3 + 1], pz = pts[p * 3 + 2];
    int pix = (int)floorf((px - PCMINX) / GRIDSZ);
    int piy = (int)floorf((py - PCMINY) / GRIDSZ);
    int piz = (int)floorf((pz - PCMINZ) / GRIDSZ);
    float density = 0.0f, logbin = 0.0f;
    float acc[NC];
#pragma unroll
    for (int c = 0; c < NC; ++c) acc[c] = 0.0f;
    for (int g = 0; g < NG; ++g) {
        float mx = means3D[g * 3 + 0], my = means3D[g * 3 + 1], mz = means3D[g * 3 + 2];
        float sx = scales[g * 3 + 0], sy = scales[g * 3 + 1], sz = scales[g * 3 + 2];
        int vx = (int)floorf((mx - PCMINX) / GRIDSZ);
        int vy = (int)floorf((my - PCMINY) / GRIDSZ);
        int vz = (int)floorf((mz - PCMINZ) / GRIDSZ);
        float smax = fmaxf(sx, fmaxf(sy, sz));
        int rad = (int)ceilf(smax * SCALE_MULTC / GRIDSZ);
        rad = rad < 1 ? 1 : rad;
        int cheb = max(abs(pix - vx), max(abs(piy - vy), abs(piz - vz)));
        if (cheb <= rad) {
            const float* r = rot3D + (size_t)g * 9;
            float dx = px - mx, dy = py - my, dz = pz - mz;
            float l0 = dx * r[0] + dy * r[3] + dz * r[6];
            float l1 = dx * r[1] + dy * r[4] + dz * r[7];
            float l2 = dx * r[2] + dy * r[5] + dz * r[8];
            float t0 = l0 / sx, t1 = l1 / sy, t2 = l2 / sz;
            float s0 = t0 * t0 + 1e-8f, s1 = t1 * t1 + 1e-8f, s2 = t2 * t2 + 1e-8f;
            float ie1 = 1.0f / uu[g], ie2 = 1.0f / vv[g], e21 = vv[g] * ie1;
            float f = __powf(__powf(s0, ie2) + __powf(s1, ie2), e21) + __powf(s2, ie1);
            float a = opas[g] * __expf(-0.5f * f);
            density += a;
            const float* sg = semantics + (size_t)g * NC;
#pragma unroll
            for (int c = 0; c < NC; ++c) acc[c] = fmaf(a, sg[c], acc[c]);
            logbin += __logf(1.0f - fminf(a, 1.0f - 1e-4f));
        }
    }
    float inv = 1.0f / (density + 1e-9f);
#pragma unroll
    for (int c = 0; c < NC; ++c) out[(size_t)p * NC + c] = acc[c] * inv;
    out[(size_t)NP * NC + p] = 1.0f - expf(logbin);
    out[(size_t)NP * NC + NP + p] = density;
}

extern "C" void kernel_launch(void* const* d_in, const int* in_sizes, int n_in,
                              void* d_out, int out_size, void* d_ws, size_t ws_size,
                              hipStream_t stream) {
    const float* pts       = (const float*)d_in[0];
    const float* means3D   = (const float*)d_in[1];
    const float* opas      = (const float*)d_in[2];
    const float* uu        = (const float*)d_in[3];
    const float* vv        = (const float*)d_in[4];
    const float* semantics = (const float*)d_in[5];
    const float* scales    = (const float*)d_in[6];
    const float* rot3D     = (const float*)d_in[7];
    float* out = (float*)d_out;

    size_t ptCntOff    = 0;
    size_t ptCntBytes  = ((size_t)NTILE * 4 + 127) & ~(size_t)127;          // 2.6 KB
    size_t candCntOff  = ptCntBytes;
    size_t candCntBytes= ((size_t)NTILE * 4 + 127) & ~(size_t)127;          // 2.6 KB
    size_t candListOff = candCntOff + candCntBytes;
    size_t candListBytes = (size_t)NTILE * 4 * SEGC * sizeof(unsigned short); // 160 KB
    size_t ptListOff   = candListOff + candListBytes;
    size_t ptListBytes = (size_t)NTILE * PCAP * sizeof(unsigned short);      // 160 KB
    size_t need = ptListOff + ptListBytes;

    if (ws_size >= need) {
        unsigned int* ptCnt      = (unsigned int*)((char*)d_ws + ptCntOff);
        unsigned int* candCnt    = (unsigned int*)((char*)d_ws + candCntOff);
        unsigned short* candList = (unsigned short*)((char*)d_ws + candListOff);
        unsigned short* ptList   = (unsigned short*)((char*)d_ws + ptListOff);
        hipMemsetAsync(ptCnt, 0, (size_t)NTILE * 4, stream);
        bin_kernel<<<NTILE + NP / 256, 256, 0, stream>>>(pts, means3D, scales,
                                                         candCnt, candList, ptCnt, ptList);
        process_kernel<<<NTILE, 64, 0, stream>>>(pts, means3D, opas, uu, vv, semantics,
                                                 scales, rot3D, candCnt, candList,
                                                 ptCnt, ptList, out);
    } else {
        agg_kernel_fb<<<NP / 64, 64, 0, stream>>>(pts, means3D, opas, uu, vv, semantics,
                                                  scales, rot3D, out);
    }
}

// Round 10
// 58.833 us; speedup vs baseline: 1.1155x; 1.1155x over previous
//
#include <hip/hip_runtime.h>
#include <math.h>

#define NP 16384
#define NG 2048
#define NC 17

#define TSH 3            // tile = 8x8 voxels in (x,y)
#define NTX 25
#define NTY 25
#define NTILE (NTX * NTY)   // 625
#define SEGC 32          // per-wave-range candidate cap (4 ranges of 512 prims)
#define CCAP (4 * SEGC)  // 128
#define PCAP 128         // per-tile point cap (Poisson mean ~26)
#define ROWF 40

#define GRIDSZ 0.4f
#define PCMINX -40.0f
#define PCMINY -40.0f
#define PCMINZ -1.0f
#define SCALE_MULTC 3.0f

// Kernel A. Blocks 0..624: prim->tile binning (ballot-compacted, per-wave
// 512-prim segment => ascending-g candidate order, deterministic, no atomics).
// Blocks 625..688: point->tile binning via atomicAdd (list ORDER nondet, but
// each point's own output depends only on candidate order => deterministic).
__global__ __launch_bounds__(256)
void bin_kernel(const float* __restrict__ pts,
                const float* __restrict__ means3D,
                const float* __restrict__ scales,
                unsigned int* __restrict__ candCnt,     // packed 4x u8 per tile
                unsigned short* __restrict__ candList,  // [NTILE][4][SEGC]
                unsigned int* __restrict__ ptCnt,       // [NTILE] (pre-zeroed)
                unsigned short* __restrict__ ptList) {  // [NTILE][PCAP]
    int b = blockIdx.x;
    int tid = threadIdx.x;
    if (b < NTILE) {
        __shared__ int wc[4];
        int lane = tid & 63, w = tid >> 6;
        int tx = b % NTX, ty = b / NTX;
        unsigned short* seg = candList + ((size_t)b * 4 + w) * SEGC;
        unsigned cl = 0;
#pragma unroll 2
        for (int it = 0; it < 8; ++it) {
            int g = w * 512 + it * 64 + lane;
            float mx = means3D[g * 3 + 0], my = means3D[g * 3 + 1];
            float sx = scales[g * 3 + 0], sy = scales[g * 3 + 1], sz = scales[g * 3 + 2];
            int vx = (int)floorf((mx - PCMINX) / GRIDSZ);
            int vy = (int)floorf((my - PCMINY) / GRIDSZ);
            float smax = fmaxf(sx, fmaxf(sy, sz));
            int rad = (int)ceilf(smax * SCALE_MULTC / GRIDSZ);
            if (rad < 1) rad = 1;
            // arithmetic >> floors negatives
            bool ov = (((vx - rad) >> TSH) <= tx) & (((vx + rad) >> TSH) >= tx) &
                      (((vy - rad) >> TSH) <= ty) & (((vy + rad) >> TSH) >= ty);
            unsigned long long bal = __ballot(ov);
            if (ov) {
                int pos = (int)cl + (int)__popcll(bal & ((1ull << lane) - 1ull));
                if (pos < SEGC) seg[pos] = (unsigned short)g;
            }
            cl += (unsigned)__popcll(bal);
        }
        if (lane == 0) wc[w] = min((int)cl, SEGC);
        __syncthreads();
        if (tid == 0)
            candCnt[b] = (unsigned)(wc[0] | (wc[1] << 8) | (wc[2] << 16) | (wc[3] << 24));
    } else {
        int p = (b - NTILE) * 256 + tid;
        float x = pts[p * 3 + 0], y = pts[p * 3 + 1];
        int jx = ((int)floorf((x - PCMINX) / GRIDSZ)) >> TSH;
        int jy = ((int)floorf((y - PCMINY) / GRIDSZ)) >> TSH;
        int t = jy * NTX + jx;
        unsigned pos = atomicAdd(&ptCnt[t], 1u);
        if (pos < PCAP) ptList[(size_t)t * PCAP + pos] = (unsigned short)p;
    }
}

// Kernel B: one block (128 thr) per tile.
// Stage: thread i builds candidate i's 40-float row in LDS (all candidate
// global loads issue concurrently). Eval: thread j = point j; candidate loop
// reads LDS broadcasts only; fully predicated evaluation.
// Row layout: [0:3] murot, [3:12] rot, [12:15] 1/scales, [15] opa,
// [16] 1/u, [17] 1/v, [18] v/u, [19] rad(int), [20:37] sem, [37:40] vx,vy,vz(int)
__global__ __launch_bounds__(128)
void process_kernel(const float* __restrict__ pts,
                    const float* __restrict__ means3D,
                    const float* __restrict__ opas,
                    const float* __restrict__ uu,
                    const float* __restrict__ vv,
                    const float* __restrict__ semantics,
                    const float* __restrict__ scales,
                    const float* __restrict__ rot3D,
                    const unsigned int* __restrict__ candCnt,
                    const unsigned short* __restrict__ candList,
                    const unsigned int* __restrict__ ptCnt,
                    const unsigned short* __restrict__ ptList,
                    float* __restrict__ out) {
    __shared__ float rows[CCAP][ROWF];   // 20 KB
    int t = blockIdx.x;
    int tid = threadIdx.x;

    unsigned cpack = candCnt[t];
    int c0 = (int)(cpack & 0xffu);
    int o1 = c0;
    int o2 = o1 + (int)((cpack >> 8) & 0xffu);
    int o3 = o2 + (int)((cpack >> 16) & 0xffu);
    int totalCand = o3 + (int)((cpack >> 24) & 0xffu);

    if (tid < totalCand) {
        int s, idx;
        if (tid < o1)      { s = 0; idx = tid; }
        else if (tid < o2) { s = 1; idx = tid - o1; }
        else if (tid < o3) { s = 2; idx = tid - o2; }
        else               { s = 3; idx = tid - o3; }
        int g = (int)candList[((size_t)t * 4 + s) * SEGC + idx];
        float mx = means3D[g * 3 + 0], my = means3D[g * 3 + 1], mz = means3D[g * 3 + 2];
        float sx = scales[g * 3 + 0], sy = scales[g * 3 + 1], sz = scales[g * 3 + 2];
        float r[9];
#pragma unroll
        for (int i = 0; i < 9; ++i) r[i] = rot3D[g * 9 + i];
        float* R = rows[tid];
        R[0] = mx * r[0] + my * r[3] + mz * r[6];
        R[1] = mx * r[1] + my * r[4] + mz * r[7];
        R[2] = mx * r[2] + my * r[5] + mz * r[8];
#pragma unroll
        for (int i = 0; i < 9; ++i) R[3 + i] = r[i];
        R[12] = 1.0f / sx; R[13] = 1.0f / sy; R[14] = 1.0f / sz;
        R[15] = opas[g];
        float ug = uu[g], vg = vv[g];
        R[16] = 1.0f / ug;
        R[17] = 1.0f / vg;
        R[18] = vg / ug;
        int vx = (int)floorf((mx - PCMINX) / GRIDSZ);
        int vy = (int)floorf((my - PCMINY) / GRIDSZ);
        int vz = (int)floorf((mz - PCMINZ) / GRIDSZ);
        float smax = fmaxf(sx, fmaxf(sy, sz));
        int rad = (int)ceilf(smax * SCALE_MULTC / GRIDSZ);
        if (rad < 1) rad = 1;
        R[19] = __int_as_float(rad);
#pragma unroll
        for (int c = 0; c < NC; ++c) R[20 + c] = semantics[(size_t)g * NC + c];
        R[37] = __int_as_float(vx);
        R[38] = __int_as_float(vy);
        R[39] = __int_as_float(vz);
    }

    __syncthreads();

    int npnt = min((int)ptCnt[t], PCAP);
    if (tid >= npnt) return;

    int p = (int)ptList[(size_t)t * PCAP + tid];
    float px = pts[p * 3 + 0], py = pts[p * 3 + 1], pz = pts[p * 3 + 2];
    int ix = (int)floorf((px - PCMINX) / GRIDSZ);
    int iy = (int)floorf((py - PCMINY) / GRIDSZ);
    int iz = (int)floorf((pz - PCMINZ) / GRIDSZ);

    float density = 0.0f, logbin = 0.0f;
    float acc[NC];
#pragma unroll
    for (int c = 0; c < NC; ++c) acc[c] = 0.0f;

    for (int k = 0; k < totalCand; ++k) {
        const float* R = rows[k];
        int cvx = __float_as_int(R[37]);
        int cvy = __float_as_int(R[38]);
        int cvz = __float_as_int(R[39]);
        int rad = __float_as_int(R[19]);
        int cheb = max(max(abs(ix - cvx), abs(iy - cvy)), abs(iz - cvz));
        float l0 = px * R[3] + py * R[6] + pz * R[9]  - R[0];
        float l1 = px * R[4] + py * R[7] + pz * R[10] - R[1];
        float l2 = px * R[5] + py * R[8] + pz * R[11] - R[2];
        float t0 = l0 * R[12], t1 = l1 * R[13], t2 = l2 * R[14];
        float s0 = t0 * t0 + 1e-8f;
        float s1 = t1 * t1 + 1e-8f;
        float s2 = t2 * t2 + 1e-8f;
        float f = __powf(__powf(s0, R[17]) + __powf(s1, R[17]), R[18]) +
                  __powf(s2, R[16]);
        float a = R[15] * __expf(-0.5f * f);
        a = (cheb <= rad) ? a : 0.0f;
        density += a;
#pragma unroll
        for (int c = 0; c < NC; ++c) acc[c] = fmaf(a, R[20 + c], acc[c]);
        logbin += __logf(1.0f - fminf(a, 1.0f - 1e-4f));
    }

    float inv = 1.0f / (density + 1e-9f);
#pragma unroll
    for (int c = 0; c < NC; ++c) out[(size_t)p * NC + c] = acc[c] * inv;
    out[(size_t)NP * NC + p] = 1.0f - expf(logbin);
    out[(size_t)NP * NC + NP + p] = density;
}

// ---- fallback (ws too small): monolithic kernel ----
__global__ __launch_bounds__(64)
void agg_kernel_fb(const float* __restrict__ pts,
                   const float* __restrict__ means3D,
                   const float* __restrict__ opas,
                   const float* __restrict__ uu,
                   const float* __restrict__ vv,
                   const float* __restrict__ semantics,
                   const float* __restrict__ scales,
                   const float* __restrict__ rot3D,
                   float* __restrict__ out) {
    int p = blockIdx.x * 64 + threadIdx.x;
    if (p >= NP) return;
    float px = pts[p * 3 + 0], py = pts[p * 3 + 1], pz = pts[p * 3 + 2];
    int pix = (int)floorf((px - PCMINX) / GRIDSZ);
    int piy = (int)floorf((py - PCMINY) / GRIDSZ);
    int piz = (int)floorf((pz - PCMINZ) / GRIDSZ);
    float density = 0.0f, logbin = 0.0f;
    float acc[NC];
#pragma unroll
    for (int c = 0; c < NC; ++c) acc[c] = 0.0f;
    for (int g = 0; g < NG; ++g) {
        float mx = means3D[g * 3 + 0], my = means3D[g * 3 + 1], mz = means3D[g * 3 + 2];
        float sx = scales[g * 3 + 0], sy = scales[g * 3 + 1], sz = scales[g * 3 + 2];
        int vx = (int)floorf((mx - PCMINX) / GRIDSZ);
        int vy = (int)floorf((my - PCMINY) / GRIDSZ);
        int vz = (int)floorf((mz - PCMINZ) / GRIDSZ);
        float smax = fmaxf(sx, fmaxf(sy, sz));
        int rad = (int)ceilf(smax * SCALE_MULTC / GRIDSZ);
        rad = rad < 1 ? 1 : rad;
        int cheb = max(abs(pix - vx), max(abs(piy - vy), abs(piz - vz)));
        if (cheb <= rad) {
            const float* r = rot3D + (size_t)g * 9;
            float dx = px - mx, dy = py - my, dz = pz - mz;
            float l0 = dx * r[0] + dy * r[3] + dz * r[6];
            float l1 = dx * r[1] + dy * r[4] + dz * r[7];
            float l2 = dx * r[2] + dy * r[5] + dz * r[8];
            float t0 = l0 / sx, t1 = l1 / sy, t2 = l2 / sz;
            float s0 = t0 * t0 + 1e-8f, s1 = t1 * t1 + 1e-8f, s2 = t2 * t2 + 1e-8f;
            float ie1 = 1.0f / uu[g], ie2 = 1.0f / vv[g], e21 = vv[g] * ie1;
            float f = __powf(__powf(s0, ie2) + __powf(s1, ie2), e21) + __powf(s2, ie1);
            float a = opas[g] * __expf(-0.5f * f);
            density += a;
            const float* sg = semantics + (size_t)g * NC;
#pragma unroll
            for (int c = 0; c < NC; ++c) acc[c] = fmaf(a, sg[c], acc[c]);
            logbin += __logf(1.0f - fminf(a, 1.0f - 1e-4f));
        }
    }
    float inv = 1.0f / (density + 1e-9f);
#pragma unroll
    for (int c = 0; c < NC; ++c) out[(size_t)p * NC + c] = acc[c] * inv;
    out[(size_t)NP * NC + p] = 1.0f - expf(logbin);
    out[(size_t)NP * NC + NP + p] = density;
}

extern "C" void kernel_launch(void* const* d_in, const int* in_sizes, int n_in,
                              void* d_out, int out_size, void* d_ws, size_t ws_size,
                              hipStream_t stream) {
    const float* pts       = (const float*)d_in[0];
    const float* means3D   = (const float*)d_in[1];
    const float* opas      = (const float*)d_in[2];
    const float* uu        = (const float*)d_in[3];
    const float* vv        = (const float*)d_in[4];
    const float* semantics = (const float*)d_in[5];
    const float* scales    = (const float*)d_in[6];
    const float* rot3D     = (const float*)d_in[7];
    float* out = (float*)d_out;

    size_t ptCntOff    = 0;
    size_t ptCntBytes  = ((size_t)NTILE * 4 + 127) & ~(size_t)127;            // 2.6 KB
    size_t candCntOff  = ptCntBytes;
    size_t candCntBytes= ((size_t)NTILE * 4 + 127) & ~(size_t)127;            // 2.6 KB
    size_t candListOff = candCntOff + candCntBytes;
    size_t candListBytes = (size_t)NTILE * 4 * SEGC * sizeof(unsigned short); // 160 KB
    size_t ptListOff   = candListOff + candListBytes;
    size_t ptListBytes = (size_t)NTILE * PCAP * sizeof(unsigned short);       // 160 KB
    size_t need = ptListOff + ptListBytes;

    if (ws_size >= need) {
        unsigned int* ptCnt      = (unsigned int*)((char*)d_ws + ptCntOff);
        unsigned int* candCnt    = (unsigned int*)((char*)d_ws + candCntOff);
        unsigned short* candList = (unsigned short*)((char*)d_ws + candListOff);
        unsigned short* ptList   = (unsigned short*)((char*)d_ws + ptListOff);
        hipMemsetAsync(ptCnt, 0, (size_t)NTILE * 4, stream);
        bin_kernel<<<NTILE + NP / 256, 256, 0, stream>>>(pts, means3D, scales,
                                                         candCnt, candList, ptCnt, ptList);
        process_kernel<<<NTILE, 128, 0, stream>>>(pts, means3D, opas, uu, vv, semantics,
                                                  scales, rot3D, candCnt, candList,
                                                  ptCnt, ptList, out);
    } else {
        agg_kernel_fb<<<NP / 64, 64, 0, stream>>>(pts, means3D, opas, uu, vv, semantics,
                                                  scales, rot3D, out);
    }
}

// Round 11
// 46.436 us; speedup vs baseline: 1.4133x; 1.2670x over previous
//
#include <hip/hip_runtime.h>
#include <math.h>

#define NP 16384
#define NG 2048
#define NC 17

#define TSH 3            // tile = 8x8 voxels in (x,y)
#define NTX 25
#define NTY 25
#define NTILE (NTX * NTY)   // 625
#define SEGC 32          // per-wave-range candidate cap (4 ranges of 512 prims)
#define CCAP (4 * SEGC)  // 128
#define PCAP 128         // per-tile point cap (Poisson mean ~26)
#define ROWF 40

#define GRIDSZ 0.4f
#define PCMINX -40.0f
#define PCMINY -40.0f
#define PCMINZ -1.0f
#define SCALE_MULTC 3.0f

// Kernel A. Blocks 0..624: prim->tile binning (ballot-compacted, per-wave
// 512-prim segment => ascending-g candidate order, deterministic, no atomics).
// Blocks 625..688: point->tile binning via atomicAdd (list ORDER nondet, but
// each point's own output depends only on candidate order => deterministic).
__global__ __launch_bounds__(256)
void bin_kernel(const float* __restrict__ pts,
                const float* __restrict__ means3D,
                const float* __restrict__ scales,
                unsigned int* __restrict__ candCnt,     // packed 4x u8 per tile
                unsigned short* __restrict__ candList,  // [NTILE][4][SEGC]
                unsigned int* __restrict__ ptCnt,       // [NTILE] (pre-zeroed)
                unsigned short* __restrict__ ptList) {  // [NTILE][PCAP]
    int b = blockIdx.x;
    int tid = threadIdx.x;
    if (b < NTILE) {
        __shared__ int wc[4];
        int lane = tid & 63, w = tid >> 6;
        int tx = b % NTX, ty = b / NTX;
        unsigned short* seg = candList + ((size_t)b * 4 + w) * SEGC;
        unsigned cl = 0;
#pragma unroll 2
        for (int it = 0; it < 8; ++it) {
            int g = w * 512 + it * 64 + lane;
            float mx = means3D[g * 3 + 0], my = means3D[g * 3 + 1];
            float sx = scales[g * 3 + 0], sy = scales[g * 3 + 1], sz = scales[g * 3 + 2];
            int vx = (int)floorf((mx - PCMINX) / GRIDSZ);
            int vy = (int)floorf((my - PCMINY) / GRIDSZ);
            float smax = fmaxf(sx, fmaxf(sy, sz));
            int rad = (int)ceilf(smax * SCALE_MULTC / GRIDSZ);
            if (rad < 1) rad = 1;
            // arithmetic >> floors negatives
            bool ov = (((vx - rad) >> TSH) <= tx) & (((vx + rad) >> TSH) >= tx) &
                      (((vy - rad) >> TSH) <= ty) & (((vy + rad) >> TSH) >= ty);
            unsigned long long bal = __ballot(ov);
            if (ov) {
                int pos = (int)cl + (int)__popcll(bal & ((1ull << lane) - 1ull));
                if (pos < SEGC) seg[pos] = (unsigned short)g;
            }
            cl += (unsigned)__popcll(bal);
        }
        if (lane == 0) wc[w] = min((int)cl, SEGC);
        __syncthreads();
        if (tid == 0)
            candCnt[b] = (unsigned)(wc[0] | (wc[1] << 8) | (wc[2] << 16) | (wc[3] << 24));
    } else {
        int p = (b - NTILE) * 256 + tid;
        float x = pts[p * 3 + 0], y = pts[p * 3 + 1];
        int jx = ((int)floorf((x - PCMINX) / GRIDSZ)) >> TSH;
        int jy = ((int)floorf((y - PCMINY) / GRIDSZ)) >> TSH;
        int t = jy * NTX + jx;
        unsigned pos = atomicAdd(&ptCnt[t], 1u);
        if (pos < PCAP) ptList[(size_t)t * PCAP + pos] = (unsigned short)p;
    }
}

// Kernel B: one block (256 thr = 4 waves) per tile.
// Stage: thread i builds candidate i's 40-float LDS row (concurrent loads).
// Eval: wave w evaluates ONLY candidate segment w for all tile points
// (lane = point, <=2 rounds); per-point partials reduced across waves via LDS.
// Fixed reduction order (w0+w1+w2+w3, ascending-g within segment) =>
// deterministic per-point result regardless of ptList ordering.
// Row layout: [0:3] murot, [3:12] rot, [12:15] 1/scales, [15] opa,
// [16] 1/u, [17] 1/v, [18] v/u, [19] rad(int), [20:37] sem, [37:40] vx,vy,vz(int)
__global__ __launch_bounds__(256)
void process_kernel(const float* __restrict__ pts,
                    const float* __restrict__ means3D,
                    const float* __restrict__ opas,
                    const float* __restrict__ uu,
                    const float* __restrict__ vv,
                    const float* __restrict__ semantics,
                    const float* __restrict__ scales,
                    const float* __restrict__ rot3D,
                    const unsigned int* __restrict__ candCnt,
                    const unsigned short* __restrict__ candList,
                    const unsigned int* __restrict__ ptCnt,
                    const unsigned short* __restrict__ ptList,
                    float* __restrict__ out) {
    __shared__ float rows[CCAP][ROWF];   // 20480 B
    __shared__ float part[3][64][21];    // 16128 B, stride 21 -> conflict-free
    int t = blockIdx.x;
    int tid = threadIdx.x;
    int lane = tid & 63, w = tid >> 6;

    unsigned cpack = candCnt[t];
    int c0 = (int)(cpack & 0xffu);
    int c1 = (int)((cpack >> 8) & 0xffu);
    int c2 = (int)((cpack >> 16) & 0xffu);
    int c3 = (int)((cpack >> 24) & 0xffu);
    int o1 = c0, o2 = o1 + c1, o3 = o2 + c2;
    int totalCand = o3 + c3;

    // ---- stage candidate rows ----
    if (tid < totalCand) {
        int s, idx;
        if (tid < o1)      { s = 0; idx = tid; }
        else if (tid < o2) { s = 1; idx = tid - o1; }
        else if (tid < o3) { s = 2; idx = tid - o2; }
        else               { s = 3; idx = tid - o3; }
        int g = (int)candList[((size_t)t * 4 + s) * SEGC + idx];
        float mx = means3D[g * 3 + 0], my = means3D[g * 3 + 1], mz = means3D[g * 3 + 2];
        float sx = scales[g * 3 + 0], sy = scales[g * 3 + 1], sz = scales[g * 3 + 2];
        float r[9];
#pragma unroll
        for (int i = 0; i < 9; ++i) r[i] = rot3D[g * 9 + i];
        float* R = rows[tid];
        R[0] = mx * r[0] + my * r[3] + mz * r[6];
        R[1] = mx * r[1] + my * r[4] + mz * r[7];
        R[2] = mx * r[2] + my * r[5] + mz * r[8];
#pragma unroll
        for (int i = 0; i < 9; ++i) R[3 + i] = r[i];
        R[12] = 1.0f / sx; R[13] = 1.0f / sy; R[14] = 1.0f / sz;
        R[15] = opas[g];
        float ug = uu[g], vg = vv[g];
        R[16] = 1.0f / ug;
        R[17] = 1.0f / vg;
        R[18] = vg / ug;
        int vx = (int)floorf((mx - PCMINX) / GRIDSZ);
        int vy = (int)floorf((my - PCMINY) / GRIDSZ);
        int vz = (int)floorf((mz - PCMINZ) / GRIDSZ);
        float smax = fmaxf(sx, fmaxf(sy, sz));
        int rad = (int)ceilf(smax * SCALE_MULTC / GRIDSZ);
        if (rad < 1) rad = 1;
        R[19] = __int_as_float(rad);
#pragma unroll
        for (int c = 0; c < NC; ++c) R[20 + c] = semantics[(size_t)g * NC + c];
        R[37] = __int_as_float(vx);
        R[38] = __int_as_float(vy);
        R[39] = __int_as_float(vz);
    }

    __syncthreads();

    int npnt = min((int)ptCnt[t], PCAP);
    int kbeg = (w == 0) ? 0 : (w == 1) ? o1 : (w == 2) ? o2 : o3;
    int kcnt = (w == 0) ? c0 : (w == 1) ? c1 : (w == 2) ? c2 : c3;
    int kend = kbeg + kcnt;

    for (int r = 0; r < 2; ++r) {
        if (r * 64 >= npnt) break;   // uniform across block
        int j = r * 64 + lane;
        bool act = j < npnt;
        int p = act ? (int)ptList[(size_t)t * PCAP + j] : 0;
        float px = pts[p * 3 + 0], py = pts[p * 3 + 1], pz = pts[p * 3 + 2];
        int ix = (int)floorf((px - PCMINX) / GRIDSZ);
        int iy = (int)floorf((py - PCMINY) / GRIDSZ);
        int iz = (int)floorf((pz - PCMINZ) / GRIDSZ);

        float density = 0.0f, logbin = 0.0f;
        float acc[NC];
#pragma unroll
        for (int c = 0; c < NC; ++c) acc[c] = 0.0f;

        for (int k = kbeg; k < kend; ++k) {
            const float* R = rows[k];
            int cvx = __float_as_int(R[37]);
            int cvy = __float_as_int(R[38]);
            int cvz = __float_as_int(R[39]);
            int rad = __float_as_int(R[19]);
            int cheb = max(max(abs(ix - cvx), abs(iy - cvy)), abs(iz - cvz));
            float l0 = px * R[3] + py * R[6] + pz * R[9]  - R[0];
            float l1 = px * R[4] + py * R[7] + pz * R[10] - R[1];
            float l2 = px * R[5] + py * R[8] + pz * R[11] - R[2];
            float t0 = l0 * R[12], t1 = l1 * R[13], t2 = l2 * R[14];
            float s0 = t0 * t0 + 1e-8f;
            float s1 = t1 * t1 + 1e-8f;
            float s2 = t2 * t2 + 1e-8f;
            float f = __powf(__powf(s0, R[17]) + __powf(s1, R[17]), R[18]) +
                      __powf(s2, R[16]);
            float a = R[15] * __expf(-0.5f * f);
            a = (cheb <= rad) ? a : 0.0f;
            density += a;
#pragma unroll
            for (int c = 0; c < NC; ++c) acc[c] = fmaf(a, R[20 + c], acc[c]);
            logbin += __logf(1.0f - fminf(a, 1.0f - 1e-4f));
        }

        if (w > 0) {
            float* pp = part[w - 1][lane];
#pragma unroll
            for (int c = 0; c < NC; ++c) pp[c] = acc[c];
            pp[17] = density;
            pp[18] = logbin;
        }
        __syncthreads();
        if (w == 0 && act) {
#pragma unroll
            for (int s = 0; s < 3; ++s) {
                const float* pp = part[s][lane];
#pragma unroll
                for (int c = 0; c < NC; ++c) acc[c] += pp[c];
                density += pp[17];
                logbin += pp[18];
            }
            float inv = 1.0f / (density + 1e-9f);
#pragma unroll
            for (int c = 0; c < NC; ++c) out[(size_t)p * NC + c] = acc[c] * inv;
            out[(size_t)NP * NC + p] = 1.0f - expf(logbin);
            out[(size_t)NP * NC + NP + p] = density;
        }
        __syncthreads();
    }
}

// ---- fallback (ws too small): monolithic kernel ----
__global__ __launch_bounds__(64)
void agg_kernel_fb(const float* __restrict__ pts,
                   const float* __restrict__ means3D,
                   const float* __restrict__ opas,
                   const float* __restrict__ uu,
                   const float* __restrict__ vv,
                   const float* __restrict__ semantics,
                   const float* __restrict__ scales,
                   const float* __restrict__ rot3D,
                   float* __restrict__ out) {
    int p = blockIdx.x * 64 + threadIdx.x;
    if (p >= NP) return;
    float px = pts[p * 3 + 0], py = pts[p * 3 + 1], pz = pts[p * 3 + 2];
    int pix = (int)floorf((px - PCMINX) / GRIDSZ);
    int piy = (int)floorf((py - PCMINY) / GRIDSZ);
    int piz = (int)floorf((pz - PCMINZ) / GRIDSZ);
    float density = 0.0f, logbin = 0.0f;
    float acc[NC];
#pragma unroll
    for (int c = 0; c < NC; ++c) acc[c] = 0.0f;
    for (int g = 0; g < NG; ++g) {
        float mx = means3D[g * 3 + 0], my = means3D[g * 3 + 1], mz = means3D[g * 3 + 2];
        float sx = scales[g * 3 + 0], sy = scales[g * 3 + 1], sz = scales[g * 3 + 2];
        int vx = (int)floorf((mx - PCMINX) / GRIDSZ);
        int vy = (int)floorf((my - PCMINY) / GRIDSZ);
        int vz = (int)floorf((mz - PCMINZ) / GRIDSZ);
        float smax = fmaxf(sx, fmaxf(sy, sz));
        int rad = (int)ceilf(smax * SCALE_MULTC / GRIDSZ);
        rad = rad < 1 ? 1 : rad;
        int cheb = max(abs(pix - vx), max(abs(piy - vy), abs(piz - vz)));
        if (cheb <= rad) {
            const float* r = rot3D + (size_t)g * 9;
            float dx = px - mx, dy = py - my, dz = pz - mz;
            float l0 = dx * r[0] + dy * r[3] + dz * r[6];
            float l1 = dx * r[1] + dy * r[4] + dz * r[7];
            float l2 = dx * r[2] + dy * r[5] + dz * r[8];
            float t0 = l0 / sx, t1 = l1 / sy, t2 = l2 / sz;
            float s0 = t0 * t0 + 1e-8f, s1 = t1 * t1 + 1e-8f, s2 = t2 * t2 + 1e-8f;
            float ie1 = 1.0f / uu[g], ie2 = 1.0f / vv[g], e21 = vv[g] * ie1;
            float f = __powf(__powf(s0, ie2) + __powf(s1, ie2), e21) + __powf(s2, ie1);
            float a = opas[g] * __expf(-0.5f * f);
            density += a;
            const float* sg = semantics + (size_t)g * NC;
#pragma unroll
            for (int c = 0; c < NC; ++c) acc[c] = fmaf(a, sg[c], acc[c]);
            logbin += __logf(1.0f - fminf(a, 1.0f - 1e-4f));
        }
    }
    float inv = 1.0f / (density + 1e-9f);
#pragma unroll
    for (int c = 0; c < NC; ++c) out[(size_t)p * NC + c] = acc[c] * inv;
    out[(size_t)NP * NC + p] = 1.0f - expf(logbin);
    out[(size_t)NP * NC + NP + p] = density;
}

extern "C" void kernel_launch(void* const* d_in, const int* in_sizes, int n_in,
                              void* d_out, int out_size, void* d_ws, size_t ws_size,
                              hipStream_t stream) {
    const float* pts       = (const float*)d_in[0];
    const float* means3D   = (const float*)d_in[1];
    const float* opas      = (const float*)d_in[2];
    const float* uu        = (const float*)d_in[3];
    const float* vv        = (const float*)d_in[4];
    const float* semantics = (const float*)d_in[5];
    const float* scales    = (const float*)d_in[6];
    const float* rot3D     = (const float*)d_in[7];
    float* out = (float*)d_out;

    size_t ptCntOff    = 0;
    size_t ptCntBytes  = ((size_t)NTILE * 4 + 127) & ~(size_t)127;            // 2.6 KB
    size_t candCntOff  = ptCntBytes;
    size_t candCntBytes= ((size_t)NTILE * 4 + 127) & ~(size_t)127;            // 2.6 KB
    size_t candListOff = candCntOff + candCntBytes;
    size_t candListBytes = (size_t)NTILE * 4 * SEGC * sizeof(unsigned short); // 160 KB
    size_t ptListOff   = candListOff + candListBytes;
    size_t ptListBytes = (size_t)NTILE * PCAP * sizeof(unsigned short);       // 160 KB
    size_t need = ptListOff + ptListBytes;

    if (ws_size >= need) {
        unsigned int* ptCnt      = (unsigned int*)((char*)d_ws + ptCntOff);
        unsigned int* candCnt    = (unsigned int*)((char*)d_ws + candCntOff);
        unsigned short* candList = (unsigned short*)((char*)d_ws + candListOff);
        unsigned short* ptList   = (unsigned short*)((char*)d_ws + ptListOff);
        hipMemsetAsync(ptCnt, 0, (size_t)NTILE * 4, stream);
        bin_kernel<<<NTILE + NP / 256, 256, 0, stream>>>(pts, means3D, scales,
                                                         candCnt, candList, ptCnt, ptList);
        process_kernel<<<NTILE, 256, 0, stream>>>(pts, means3D, opas, uu, vv, semantics,
                                                  scales, rot3D, candCnt, candList,
                                                  ptCnt, ptList, out);
    } else {
        agg_kernel_fb<<<NP / 64, 64, 0, stream>>>(pts, means3D, opas, uu, vv, semantics,
                                                  scales, rot3D, out);
    }
}